// Round 15
// baseline (157.068 us; speedup 1.0000x reference)
//
#include <hip/hip_runtime.h>
#include <math.h>

// KerasCustomMappingLayer: B=32768 rows x H=512 sequential steps, out (B,H,6) f32.
//
// R15 = R14 (proven 152.0us) with ONE change: WAVE-LOCAL phase sync.
//   - The block-shared per-phase s_w wall table is eliminated: B computes
//     walls inline from s_lk (hl = lk*0.5; wl = blo+hl; wr = bhi-hl) with a
//     head cndmask (cd = head ? d : wall_cd) -- R13-proven form, bit-identical
//     (at a head the owning pair has p==0, so _c = 0 + r = r exactly).
//   - With s_w gone, ALL per-phase arrays (bd_pk, bd_xy, bd_h) are per-wave;
//     s_lk/seg_list/s_S are read-only after setup. The 3 per-phase block-wide
//     __syncthreads become wave-local WFENCE (s_waitcnt lgkmcnt(0) +
//     sched_barrier(0)) -- correctness of this fence proven in R10 (passed).
//     Waves free-run: no inter-wave B-skew stalls; barriers/row 14 -> 2.
//   - Only 2 fences per phase needed (after A: bd_pk ready; after B: bd_xy
//     ready). C's bd_xy reads complete before B(h+1) writes because the
//     post-A(h+1) fence orders them; A(h+1)'s bd_pk writes conflict only
//     with B(h) reads, ordered by the post-B fence.
//   LDS ~16.5KB -> 8 blocks/CU retained.
// R14 lessons kept: pair-split B (lane parity = chain), rebased slots,
// LDS carry handoff. R13: branchless select. R12: HALF=128. R11: packed bd_*,
// folded advance. R10: single-axis. Numerics: carry path bit-identical to
// numpy fp32 (contract off, IEEE div/sqrt); outputs *1/512 pow2-exact,
// *1/384 <=1ulp output-only (absmax 0.0078125 stable R8-R14).
// Frozen: plain stores (R2/R4), dense global access (R1), no VGPR squeeze (R5).

#define H 512
#define RPB 4      // rows per block = waves per block
#define HALF 128   // k-steps staged per phase
#define NPH (H / HALF)
#define JPP (HALF / 64)   // j-iterations per phase
#define SLOTS 5    // 5*32 pairs = 160 >= max segments intersecting a phase

typedef float v2f __attribute__((ext_vector_type(2)));
typedef float v4f __attribute__((ext_vector_type(4)));

#define WFENCE() do { \
    asm volatile("s_waitcnt lgkmcnt(0)" ::: "memory"); \
    __builtin_amdgcn_sched_barrier(0); \
} while (0)

__global__ __launch_bounds__(256, 4)
void construct_map_seg(const float* __restrict__ mapvars,
                       const float* __restrict__ rel,
                       const float* __restrict__ start_pos,
                       const float* __restrict__ lmul,
                       const int* __restrict__ nfse_p,
                       float* __restrict__ out)
{
#pragma clang fp contract(off)
    __shared__ float s_lk[H];
    __shared__ int   seg_list[H + 8];
    __shared__ int   nseg_s;
    __shared__ int   s_S[NPH];              // first segment intersecting each phase
    __shared__ float2 bd_pk[RPB][HALF * 2]; // per-wave: {d_or_r, advance} per (kk,par)
    __shared__ float2 bd_xy[RPB][HALF];     // per-wave: {_x,_y} results
    __shared__ float  bd_h[RPB][2];         // per-wave: phase-crossing carry per chain

    const int tid = threadIdx.x;
    const int w = tid >> 6;
    const int lane = tid & 63;
    const int pair = lane >> 1;
    const int par = lane & 1;
    const int row = blockIdx.x * RPB + w;

    const float lm = lmul[0];
    for (int i = tid; i < H; i += 256)
        s_lk[i] = __fmul_rn(lm, rel[5 * H + i]);   // l = lmul * note_dist
    __syncthreads();

    // segment list: starts = {0} U {k : l[k] > 192}  (k-only, all rows share)
    if (tid < 64) {
        int base = 0;
        for (int c = 0; c < H / 64; ++c) {
            int k = c * 64 + tid;
            bool isr = (k == 0) || (s_lk[k] > 192.0f);
            unsigned long long m = __ballot(isr);
            int idx = base + __popcll(m & ((1ull << tid) - 1ull));
            if (isr) seg_list[idx] = k;
            base += __popcll(m);
        }
        if (tid == 0) { seg_list[base] = H; nseg_s = base; }
        // per-phase first-intersecting segment: S_h = (first idx > kb) - 1
        if (tid < NPH) {
            int kb = tid * HALF;
            int lo = 0, hi = base + 1;
            while (lo < hi) { int m = (lo + hi) >> 1; if (seg_list[m] <= kb) lo = m + 1; else hi = m; }
            s_S[tid] = lo - 1;                     // seg_list[0]=0 => S>=0
        }
    }
    __syncthreads();                               // last block-wide barrier

    const int nseg = nseg_s;
    const bool nfse = (nfse_p[0] != 0);
    const float sx = start_pos[0], sy = start_pos[1];

    const float WL = (float)(0.05 * 512.0);
    const float WR = (float)(0.95 * 512.0);
    const float WT = (float)(0.05 * 384.0);
    const float WB = (float)(0.95 * 384.0);
    const float blo = par ? WT : WL;               // per-chain wall bases
    const float bhi = par ? WB : WR;

    // fresh-segment init for k==0: start_pos unless k==0 is itself a rerand head
    const bool head0 = s_lk[0] > 192.0f;
    const float pinit0 = head0 ? 0.0f : (par ? sy : sx);

    const float* rowp = mapvars + (size_t)row * (4 * H);
    float* orow = out + (size_t)row * (H * 6);

    for (int h = 0; h < NPH; ++h) {
        const int kb = h * HALF;
        const int kend = kb + HALF;
        float o2r[JPP], o3r[JPP], e1r[JPP], e2r[JPP];

        // ---- A: heavy per-k math, dense, all lanes active ----
#pragma unroll
        for (int j = 0; j < JPP; ++j) {
            const int kk = lane + 64 * j;
            const int k = kb + kk;
            float m0 = rowp[k];
            float m1 = rowp[H + k];
            float m2 = rowp[2 * H + k];
            float m3 = rowp[3 * H + k];
            float sln  = rel[H + k];
            float scos = rel[3 * H + k];
            float ssin = rel[4 * H + k];
            float lk  = s_lk[k];
            float isf = rel[k];                       // is_slider (L2-broadcast)

            float len1 = __fsqrt_rn(__fadd_rn(__fmul_rn(m0, m0), __fmul_rn(m2, m2)));
            float ck = __fdiv_rn(m0, len1);
            float sk = __fdiv_rn(m2, len1);
            float len2 = __fsqrt_rn(__fadd_rn(__fmul_rn(m1, m1), __fmul_rn(m3, m3)));
            float ck2 = __fdiv_rn(m1, len2);
            float sk2 = __fdiv_rn(m3, len2);

            float dx = __fmul_rn(lk, ck);
            float dy = __fmul_rn(lk, sk);
            float rx = __fadd_rn(256.0f, __fmul_rn(256.0f, m0));
            float ry = __fadd_rn(192.0f, __fmul_rn(192.0f, m2));
            float e1 = __fmul_rn(ck2, sln);
            float e2 = __fmul_rn(sk2, sln);
            bool rr  = lk > 192.0f;                   // head position
            bool isl = isf != 0.0f;
            float oa = __fadd_rn(__fmul_rn(ck2, scos), -__fmul_rn(sk2, ssin));
            float ob = __fadd_rn(__fmul_rn(ck2, ssin),  __fmul_rn(sk2, scos));
            o2r[j] = isl ? oa : (rr ? ck2 : ck);
            o3r[j] = isl ? ob : (rr ? sk2 : sk);
            e1r[j] = e1; e2r[j] = e2;

            bool adv = isl && nfse;
            v4f pk4 = {rr ? rx : dx, adv ? e1 : 0.0f,
                       rr ? ry : dy, adv ? e2 : 0.0f};
            *(v4f*)&bd_pk[w][2 * kk] = pk4;           // one b128 store
        }
        WFENCE();   // bd_pk ready (wave-local: per-wave array, lockstep wave)

        // ---- B: serial carry chain, pair-split, inline walls ----
        {
            const int S = s_S[h];
#pragma unroll
            for (int slot = 0; slot < SLOTS; ++slot) {
                const int sid = S + pair + 32 * slot;
                if (sid < nseg) {
                    const int k0 = seg_list[sid];
                    const int k1 = seg_list[sid + 1];
                    const int lo = (k0 > kb) ? k0 : kb;
                    const int hi = (k1 < kend) ? k1 : kend;
                    if (lo < hi) {
                        float p;
                        if (k0 < kb)      p = bd_h[w][par];     // crossing-in
                        else if (k0 == 0) p = pinit0;
                        else              p = 0.0f;             // fresh head segment
                        for (int k = lo; k < hi; ++k) {
                            const int kk = k - kb;
                            float lk = s_lk[k];
                            float2 pk = bd_pk[w][2 * kk + par];
                            float d = pk.x, a = pk.y;
                            bool head = lk > 192.0f;
                            float hl = __fmul_rn(lk, 0.5f);
                            float wlv = __fadd_rn(blo, hl);
                            float whv = __fadd_rn(bhi, -hl);
                            float ad = fabsf(d);
                            float cd = (p < wlv) ? ad
                                     : ((p > whv) ? -ad
                                     : (((p > wlv) && (p < whv)) ? d : 0.0f));
                            cd = head ? d : cd;                 // head: p==0, _c = r
                            float _c = __fadd_rn(p, cd);
                            ((float*)&bd_xy[w][kk])[par] = _c;
                            p = __fadd_rn(_c, a);               // +0.0 bit-safe
                        }
                        if (k1 > kend) bd_h[w][par] = p;        // crossing-out (unique)
                    }
                }
            }
        }
        WFENCE();   // bd_xy (+ handoff) ready for C; also orders B reads vs next-A writes

        // ---- C: output assembly, dense stores ----
#pragma unroll
        for (int j = 0; j < JPP; ++j) {
            const int kk = lane + 64 * j;
            const int k = kb + kk;
            float2 xy = bd_xy[w][kk];
            float _x = xy.x, _y = xy.y;
            float o0 = __fmul_rn(_x, 1.0f / 512.0f);
            float o1 = __fmul_rn(_y, 1.0f / 384.0f);
            bool isl = rel[k] != 0.0f;
            float o4 = o0, o5 = o1;
            if (isl) {
                o4 = __fmul_rn(__fadd_rn(_x, e1r[j]), 1.0f / 512.0f);
                o5 = __fmul_rn(__fadd_rn(_y, e2r[j]), 1.0f / 384.0f);
            }
            float* op = orow + (size_t)k * 6;
            v2f a = {o0, o1};
            v2f b = {o2r[j], o3r[j]};
            v2f c = {o4, o5};
            *(v2f*)(op)     = a;
            *(v2f*)(op + 2) = b;
            *(v2f*)(op + 4) = c;
        }
        // no fence needed here: C reads bd_xy; B(h+1)'s bd_xy writes are
        // ordered behind the post-A(h+1) WFENCE; A(h+1) writes only bd_pk,
        // whose last readers (B(h)) completed before the post-B fence.
    }
}

extern "C" void kernel_launch(void* const* d_in, const int* in_sizes, int n_in,
                              void* d_out, int out_size, void* d_ws, size_t ws_size,
                              hipStream_t stream) {
    const float* mapvars = (const float*)d_in[0];
    const float* rel     = (const float*)d_in[1];
    const float* sp      = (const float*)d_in[2];
    const float* lm      = (const float*)d_in[3];
    const int*   nfse    = (const int*)d_in[4];
    float* out = (float*)d_out;

    const int B = in_sizes[0] / (4 * H);   // 32768
    hipLaunchKernelGGL(construct_map_seg, dim3(B / RPB), dim3(256), 0, stream,
                       mapvars, rel, sp, lm, nfse, out);
}

// Round 16
// 152.475 us; speedup vs baseline: 1.0301x; 1.0301x over previous
//
#include <hip/hip_runtime.h>
#include <math.h>

// KerasCustomMappingLayer: B=32768 rows x H=512 sequential steps, out (B,H,6) f32.
//
// R16 = R14 (proven 152.0us; R15's wave-local-fence experiment regressed to
// 157 and is fully reverted) with ONE change: 1-AHEAD ROTATE-PREFETCH in B.
//   B's dynamic k-loop previously issued ds_read(s_w) + ds_read(bd_pk) and
//   waited lgkmcnt(0) before each step's ~12-VALU chain: ~60-90cy LDS latency
//   exposed per serial step (~100 steps/row = the largest non-memory term).
//   Now each iteration consumes preloaded {w2,pk} and issues the k+1 loads
//   (clamped to hi-1; harmless reload on the last step) BEFORE the compute
//   chain, so the wait lands after ~28cy of useful work. Same loads, same
//   value-path ops, same order => bit-identical.
// R14 lessons kept: pair-split B, block-shared s_w wall table ({-inf,+inf}
// at heads), rebased slots, LDS carry handoff, __syncthreads phase sync
// (R15 proved barrier skew is small; fences+sched_barrier regressed).
// R13: branchless select. R12: HALF=128, 8 blocks/CU. R11: packed bd_*,
// folded advance (+0.0 bit-safe). R10: single-axis changes only.
// Numerics: carry path bit-identical to numpy fp32 (contract off, IEEE
// div/sqrt; walls blo+hl / bhi-hl computed once per block). Outputs *1/512
// pow2-exact, *1/384 <=1ulp output-only (absmax 0.0078125 stable R8-R15).
// Frozen: plain stores (R2/R4), dense global access (R1), no VGPR squeeze (R5).

#define H 512
#define RPB 4      // rows per block = waves per block
#define HALF 128   // k-steps staged per phase
#define NPH (H / HALF)
#define JPP (HALF / 64)   // j-iterations per phase
#define SLOTS 5    // 5*32 pairs = 160 >= max segments intersecting a phase

typedef float v2f __attribute__((ext_vector_type(2)));
typedef float v4f __attribute__((ext_vector_type(4)));

__global__ __launch_bounds__(256, 4)
void construct_map_seg(const float* __restrict__ mapvars,
                       const float* __restrict__ rel,
                       const float* __restrict__ start_pos,
                       const float* __restrict__ lmul,
                       const int* __restrict__ nfse_p,
                       float* __restrict__ out)
{
#pragma clang fp contract(off)
    __shared__ float s_lk[H];
    __shared__ int   seg_list[H + 8];
    __shared__ int   nseg_s;
    __shared__ int   s_S[NPH];            // first segment intersecting each phase
    __shared__ float2 s_w[HALF * 2];      // block-shared: {wlo,whi} per (kk,par); heads {-inf,+inf}
    __shared__ float2 bd_pk[RPB][HALF * 2]; // per-wave: {d_or_r, advance} per (kk,par)
    __shared__ float2 bd_xy[RPB][HALF];   // {_x,_y} results
    __shared__ float  bd_h[RPB][2];       // phase-crossing carry per chain

    const int tid = threadIdx.x;
    const int w = tid >> 6;
    const int lane = tid & 63;
    const int pair = lane >> 1;
    const int par = lane & 1;
    const int row = blockIdx.x * RPB + w;

    const float lm = lmul[0];
    for (int i = tid; i < H; i += 256)
        s_lk[i] = __fmul_rn(lm, rel[5 * H + i]);   // l = lmul * note_dist
    __syncthreads();

    // segment list: starts = {0} U {k : l[k] > 192}  (k-only, all rows share)
    if (tid < 64) {
        int base = 0;
        for (int c = 0; c < H / 64; ++c) {
            int k = c * 64 + tid;
            bool isr = (k == 0) || (s_lk[k] > 192.0f);
            unsigned long long m = __ballot(isr);
            int idx = base + __popcll(m & ((1ull << tid) - 1ull));
            if (isr) seg_list[idx] = k;
            base += __popcll(m);
        }
        if (tid == 0) { seg_list[base] = H; nseg_s = base; }
        // per-phase first-intersecting segment: S_h = (first idx > kb) - 1
        if (tid < NPH) {
            int kb = tid * HALF;
            int lo = 0, hi = base + 1;                 // search idx range [0, nseg]
            while (lo < hi) { int m = (lo + hi) >> 1; if (seg_list[m] <= kb) lo = m + 1; else hi = m; }
            s_S[tid] = lo - 1;                         // seg_list[0]=0 => S>=0
        }
    }
    __syncthreads();

    const int nseg = nseg_s;
    const bool nfse = (nfse_p[0] != 0);
    const float sx = start_pos[0], sy = start_pos[1];

    const float WL = (float)(0.05 * 512.0);
    const float WR = (float)(0.95 * 512.0);
    const float WT = (float)(0.05 * 384.0);
    const float WB = (float)(0.95 * 384.0);

    // fresh-segment init for k==0: start_pos unless k==0 is itself a rerand head
    const bool head0 = s_lk[0] > 192.0f;
    const float pinit0 = head0 ? 0.0f : (par ? sy : sx);

    const float* rowp = mapvars + (size_t)row * (4 * H);
    float* orow = out + (size_t)row * (H * 6);

    for (int h = 0; h < NPH; ++h) {
        const int kb = h * HALF;
        const int kend = kb + HALF;
        float o2r[JPP], o3r[JPP], e1r[JPP], e2r[JPP];

        // ---- wall table for this phase (block-shared, row-independent) ----
        {
            const int i = tid;                 // 256 threads == HALF*2 entries
            const int kkw = i >> 1, prw = i & 1;
            float lk = s_lk[kb + kkw];
            bool head = lk > 192.0f;
            float hl = __fmul_rn(lk, 0.5f);
            float blo = prw ? WT : WL;
            float bhi = prw ? WB : WR;
            v2f w2 = {head ? -INFINITY : __fadd_rn(blo, hl),
                      head ?  INFINITY : __fadd_rn(bhi, -hl)};
            *(v2f*)&s_w[i] = w2;
        }

        // ---- A: heavy per-k math, dense, all lanes active ----
#pragma unroll
        for (int j = 0; j < JPP; ++j) {
            const int kk = lane + 64 * j;
            const int k = kb + kk;
            float m0 = rowp[k];
            float m1 = rowp[H + k];
            float m2 = rowp[2 * H + k];
            float m3 = rowp[3 * H + k];
            float sln  = rel[H + k];
            float scos = rel[3 * H + k];
            float ssin = rel[4 * H + k];
            float lk  = s_lk[k];
            float isf = rel[k];                       // is_slider (L2-broadcast)

            float len1 = __fsqrt_rn(__fadd_rn(__fmul_rn(m0, m0), __fmul_rn(m2, m2)));
            float ck = __fdiv_rn(m0, len1);
            float sk = __fdiv_rn(m2, len1);
            float len2 = __fsqrt_rn(__fadd_rn(__fmul_rn(m1, m1), __fmul_rn(m3, m3)));
            float ck2 = __fdiv_rn(m1, len2);
            float sk2 = __fdiv_rn(m3, len2);

            float dx = __fmul_rn(lk, ck);
            float dy = __fmul_rn(lk, sk);
            float rx = __fadd_rn(256.0f, __fmul_rn(256.0f, m0));
            float ry = __fadd_rn(192.0f, __fmul_rn(192.0f, m2));
            float e1 = __fmul_rn(ck2, sln);
            float e2 = __fmul_rn(sk2, sln);
            bool rr  = lk > 192.0f;                   // head position
            bool isl = isf != 0.0f;
            float oa = __fadd_rn(__fmul_rn(ck2, scos), -__fmul_rn(sk2, ssin));
            float ob = __fadd_rn(__fmul_rn(ck2, ssin),  __fmul_rn(sk2, scos));
            o2r[j] = isl ? oa : (rr ? ck2 : ck);
            o3r[j] = isl ? ob : (rr ? sk2 : sk);
            e1r[j] = e1; e2r[j] = e2;

            bool adv = isl && nfse;
            v4f pk4 = {rr ? rx : dx, adv ? e1 : 0.0f,
                       rr ? ry : dy, adv ? e2 : 0.0f};
            *(v4f*)&bd_pk[w][2 * kk] = pk4;           // one b128 store
        }
        __syncthreads();

        // ---- B: serial carry chain, pair-split, 1-ahead rotate prefetch ----
        {
            const int S = s_S[h];
#pragma unroll
            for (int slot = 0; slot < SLOTS; ++slot) {
                const int sid = S + pair + 32 * slot;
                if (sid < nseg) {
                    const int k0 = seg_list[sid];
                    const int k1 = seg_list[sid + 1];
                    const int lo = (k0 > kb) ? k0 : kb;
                    const int hi = (k1 < kend) ? k1 : kend;
                    if (lo < hi) {
                        float p;
                        if (k0 < kb)      p = bd_h[w][par];     // crossing-in
                        else if (k0 == 0) p = pinit0;
                        else              p = 0.0f;             // fresh head segment
                        // preload step lo
                        float2 w2 = s_w[2 * (lo - kb) + par];
                        float2 pk = bd_pk[w][2 * (lo - kb) + par];
                        for (int k = lo; k < hi; ++k) {
                            const int kk = k - kb;
                            float2 w2c = w2;
                            float2 pkc = pk;
                            // issue next step's loads before the compute chain
                            const int kn = (k + 1 < hi) ? (k + 1 - kb) : kk;
                            w2 = s_w[2 * kn + par];
                            pk = bd_pk[w][2 * kn + par];
                            float d = pkc.x, a = pkc.y;
                            float ad = fabsf(d);
                            float cd = (p < w2c.x) ? ad
                                     : ((p > w2c.y) ? -ad
                                     : (((p > w2c.x) && (p < w2c.y)) ? d : 0.0f));
                            float _c = __fadd_rn(p, cd);        // head: 0 + r = r
                            ((float*)&bd_xy[w][kk])[par] = _c;
                            p = __fadd_rn(_c, a);               // +0.0 bit-safe
                        }
                        if (k1 > kend) bd_h[w][par] = p;        // crossing-out (unique)
                    }
                }
            }
        }
        __syncthreads();

        // ---- C: output assembly, dense stores ----
#pragma unroll
        for (int j = 0; j < JPP; ++j) {
            const int kk = lane + 64 * j;
            const int k = kb + kk;
            float2 xy = bd_xy[w][kk];
            float _x = xy.x, _y = xy.y;
            float o0 = __fmul_rn(_x, 1.0f / 512.0f);
            float o1 = __fmul_rn(_y, 1.0f / 384.0f);
            bool isl = rel[k] != 0.0f;
            float o4 = o0, o5 = o1;
            if (isl) {
                o4 = __fmul_rn(__fadd_rn(_x, e1r[j]), 1.0f / 512.0f);
                o5 = __fmul_rn(__fadd_rn(_y, e2r[j]), 1.0f / 384.0f);
            }
            float* op = orow + (size_t)k * 6;
            v2f a = {o0, o1};
            v2f b = {o2r[j], o3r[j]};
            v2f c = {o4, o5};
            *(v2f*)(op)     = a;
            *(v2f*)(op + 2) = b;
            *(v2f*)(op + 4) = c;
        }
        __syncthreads();
    }
}

extern "C" void kernel_launch(void* const* d_in, const int* in_sizes, int n_in,
                              void* d_out, int out_size, void* d_ws, size_t ws_size,
                              hipStream_t stream) {
    const float* mapvars = (const float*)d_in[0];
    const float* rel     = (const float*)d_in[1];
    const float* sp      = (const float*)d_in[2];
    const float* lm      = (const float*)d_in[3];
    const int*   nfse    = (const int*)d_in[4];
    float* out = (float*)d_out;

    const int B = in_sizes[0] / (4 * H);   // 32768
    hipLaunchKernelGGL(construct_map_seg, dim3(B / RPB), dim3(256), 0, stream,
                       mapvars, rel, sp, lm, nfse, out);
}

// Round 17
// 145.506 us; speedup vs baseline: 1.0795x; 1.0479x over previous
//
#include <hip/hip_runtime.h>
#include <math.h>

// KerasCustomMappingLayer: B=32768 rows x H=512 sequential steps, out (B,H,6) f32.
//
// R17 = R14 (proven 152.0us) with ONE subsystem change: CROSS-PHASE LOAD
// PIPELINE with non-draining barriers (T14/T4 adapted).
//   - __syncthreads lowers to "s_waitcnt vmcnt(0) lgkmcnt(0); s_barrier":
//     every phase barrier drained ALL global loads -> memory and compute
//     alternated (sum) instead of overlapping (max). That was the ~60us gap
//     (R16 falsified the B-LDS-latency hypothesis: prefetch was neutral).
//   - Now: mapvars for phase h+1 are issued into 8 registers during A(h);
//     the 3 per-phase barriers become {s_waitcnt lgkmcnt(0); s_barrier} --
//     LDS producer/consumer visibility preserved (all B/C need), but the
//     prefetched HBM loads stay in flight through B(h)+C(h) (~50us of
//     compute) and are waited only at A(h+1)'s first register use.
//   - No sched_barrier (R15 lesson: it pins the scheduler and regresses).
//     rel[] loads stay in A: L2-broadcast (same address block-wide), cheap.
//   - B phase: R14's plain form (R16's rotate-prefetch was neutral, reverted).
//   - VGPR risk: 48 -> ~60; must stay <=64 for 8 waves/SIMD. launch_bounds
//     stays (256,4) (R5: forcing 8 squeezed VGPR to 32 and spilled).
// Numerics: identical ops in identical order; only load timing changed.
// Carry path bit-identical to numpy fp32 (contract off, IEEE div/sqrt;
// walls from block-shared s_w table, heads={-inf,+inf}). Outputs *1/512
// pow2-exact, *1/384 <=1ulp output-only (absmax 0.0078125 stable R8-R16).
// Frozen: plain stores (R2/R4), dense global access (R1), HALF=128 (R12),
// pair-split B + s_w table (R14), single-axis change (R10).

#define H 512
#define RPB 4      // rows per block = waves per block
#define HALF 128   // k-steps staged per phase
#define NPH (H / HALF)
#define JPP (HALF / 64)   // j-iterations per phase
#define SLOTS 5    // 5*32 pairs = 160 >= max segments intersecting a phase

typedef float v2f __attribute__((ext_vector_type(2)));
typedef float v4f __attribute__((ext_vector_type(4)));

// block barrier WITHOUT vmcnt drain: LDS visibility only
#define PBAR() do { \
    asm volatile("s_waitcnt lgkmcnt(0)" ::: "memory"); \
    __builtin_amdgcn_s_barrier(); \
} while (0)

__global__ __launch_bounds__(256, 4)
void construct_map_seg(const float* __restrict__ mapvars,
                       const float* __restrict__ rel,
                       const float* __restrict__ start_pos,
                       const float* __restrict__ lmul,
                       const int* __restrict__ nfse_p,
                       float* __restrict__ out)
{
#pragma clang fp contract(off)
    __shared__ float s_lk[H];
    __shared__ int   seg_list[H + 8];
    __shared__ int   nseg_s;
    __shared__ int   s_S[NPH];            // first segment intersecting each phase
    __shared__ float2 s_w[HALF * 2];      // block-shared: {wlo,whi} per (kk,par); heads {-inf,+inf}
    __shared__ float2 bd_pk[RPB][HALF * 2]; // per-wave: {d_or_r, advance} per (kk,par)
    __shared__ float2 bd_xy[RPB][HALF];   // {_x,_y} results
    __shared__ float  bd_h[RPB][2];       // phase-crossing carry per chain

    const int tid = threadIdx.x;
    const int w = tid >> 6;
    const int lane = tid & 63;
    const int pair = lane >> 1;
    const int par = lane & 1;
    const int row = blockIdx.x * RPB + w;

    const float lm = lmul[0];
    for (int i = tid; i < H; i += 256)
        s_lk[i] = __fmul_rn(lm, rel[5 * H + i]);   // l = lmul * note_dist
    __syncthreads();

    // segment list: starts = {0} U {k : l[k] > 192}  (k-only, all rows share)
    if (tid < 64) {
        int base = 0;
        for (int c = 0; c < H / 64; ++c) {
            int k = c * 64 + tid;
            bool isr = (k == 0) || (s_lk[k] > 192.0f);
            unsigned long long m = __ballot(isr);
            int idx = base + __popcll(m & ((1ull << tid) - 1ull));
            if (isr) seg_list[idx] = k;
            base += __popcll(m);
        }
        if (tid == 0) { seg_list[base] = H; nseg_s = base; }
        // per-phase first-intersecting segment: S_h = (first idx > kb) - 1
        if (tid < NPH) {
            int kb = tid * HALF;
            int lo = 0, hi = base + 1;                 // search idx range [0, nseg]
            while (lo < hi) { int m = (lo + hi) >> 1; if (seg_list[m] <= kb) lo = m + 1; else hi = m; }
            s_S[tid] = lo - 1;                         // seg_list[0]=0 => S>=0
        }
    }
    __syncthreads();

    const int nseg = nseg_s;
    const bool nfse = (nfse_p[0] != 0);
    const float sx = start_pos[0], sy = start_pos[1];

    const float WL = (float)(0.05 * 512.0);
    const float WR = (float)(0.95 * 512.0);
    const float WT = (float)(0.05 * 384.0);
    const float WB = (float)(0.95 * 384.0);

    // fresh-segment init for k==0: start_pos unless k==0 is itself a rerand head
    const bool head0 = s_lk[0] > 192.0f;
    const float pinit0 = head0 ? 0.0f : (par ? sy : sx);

    const float* rowp = mapvars + (size_t)row * (4 * H);
    float* orow = out + (size_t)row * (H * 6);

    // ---- cross-phase register prefetch of mapvars (8 VGPRs) ----
    float pf[JPP][4];
#pragma unroll
    for (int j = 0; j < JPP; ++j) {
        const int k = lane + 64 * j;                  // phase 0
        pf[j][0] = rowp[k];
        pf[j][1] = rowp[H + k];
        pf[j][2] = rowp[2 * H + k];
        pf[j][3] = rowp[3 * H + k];
    }

    for (int h = 0; h < NPH; ++h) {
        const int kb = h * HALF;
        const int kend = kb + HALF;
        const int kbn = ((h + 1) & (NPH - 1)) * HALF; // next phase base (wraps; wrap loads are harmless reloads)
        float o2r[JPP], o3r[JPP], e1r[JPP], e2r[JPP];

        // ---- wall table for this phase (block-shared, row-independent) ----
        {
            const int i = tid;                 // 256 threads == HALF*2 entries
            const int kkw = i >> 1, prw = i & 1;
            float lk = s_lk[kb + kkw];
            bool head = lk > 192.0f;
            float hl = __fmul_rn(lk, 0.5f);
            float blo = prw ? WT : WL;
            float bhi = prw ? WB : WR;
            v2f w2 = {head ? -INFINITY : __fadd_rn(blo, hl),
                      head ?  INFINITY : __fadd_rn(bhi, -hl)};
            *(v2f*)&s_w[i] = w2;
        }

        // ---- A: consume prefetched regs, compute, issue next-phase loads ----
#pragma unroll
        for (int j = 0; j < JPP; ++j) {
            const int kk = lane + 64 * j;
            const int k = kb + kk;
            float m0 = pf[j][0];
            float m1 = pf[j][1];
            float m2 = pf[j][2];
            float m3 = pf[j][3];
            // issue next phase's loads immediately after consuming this j's regs
            {
                const int kn = kbn + kk;
                pf[j][0] = rowp[kn];
                pf[j][1] = rowp[H + kn];
                pf[j][2] = rowp[2 * H + kn];
                pf[j][3] = rowp[3 * H + kn];
            }
            float sln  = rel[H + k];
            float scos = rel[3 * H + k];
            float ssin = rel[4 * H + k];
            float lk  = s_lk[k];
            float isf = rel[k];                       // is_slider (L2-broadcast)

            float len1 = __fsqrt_rn(__fadd_rn(__fmul_rn(m0, m0), __fmul_rn(m2, m2)));
            float ck = __fdiv_rn(m0, len1);
            float sk = __fdiv_rn(m2, len1);
            float len2 = __fsqrt_rn(__fadd_rn(__fmul_rn(m1, m1), __fmul_rn(m3, m3)));
            float ck2 = __fdiv_rn(m1, len2);
            float sk2 = __fdiv_rn(m3, len2);

            float dx = __fmul_rn(lk, ck);
            float dy = __fmul_rn(lk, sk);
            float rx = __fadd_rn(256.0f, __fmul_rn(256.0f, m0));
            float ry = __fadd_rn(192.0f, __fmul_rn(192.0f, m2));
            float e1 = __fmul_rn(ck2, sln);
            float e2 = __fmul_rn(sk2, sln);
            bool rr  = lk > 192.0f;                   // head position
            bool isl = isf != 0.0f;
            float oa = __fadd_rn(__fmul_rn(ck2, scos), -__fmul_rn(sk2, ssin));
            float ob = __fadd_rn(__fmul_rn(ck2, ssin),  __fmul_rn(sk2, scos));
            o2r[j] = isl ? oa : (rr ? ck2 : ck);
            o3r[j] = isl ? ob : (rr ? sk2 : sk);
            e1r[j] = e1; e2r[j] = e2;

            bool adv = isl && nfse;
            v4f pk4 = {rr ? rx : dx, adv ? e1 : 0.0f,
                       rr ? ry : dy, adv ? e2 : 0.0f};
            *(v4f*)&bd_pk[w][2 * kk] = pk4;           // one b128 store
        }
        PBAR();   // LDS visibility only; prefetched loads stay in flight

        // ---- B: serial carry chain, pair-split (R14 form) ----
        {
            const int S = s_S[h];
#pragma unroll
            for (int slot = 0; slot < SLOTS; ++slot) {
                const int sid = S + pair + 32 * slot;
                if (sid < nseg) {
                    const int k0 = seg_list[sid];
                    const int k1 = seg_list[sid + 1];
                    const int lo = (k0 > kb) ? k0 : kb;
                    const int hi = (k1 < kend) ? k1 : kend;
                    if (lo < hi) {
                        float p;
                        if (k0 < kb)      p = bd_h[w][par];     // crossing-in
                        else if (k0 == 0) p = pinit0;
                        else              p = 0.0f;             // fresh head segment
                        for (int k = lo; k < hi; ++k) {
                            const int kk = k - kb;
                            float2 w2 = s_w[2 * kk + par];
                            float2 pk = bd_pk[w][2 * kk + par];
                            float d = pk.x, a = pk.y;
                            float ad = fabsf(d);
                            float cd = (p < w2.x) ? ad
                                     : ((p > w2.y) ? -ad
                                     : (((p > w2.x) && (p < w2.y)) ? d : 0.0f));
                            float _c = __fadd_rn(p, cd);        // head: 0 + r = r
                            ((float*)&bd_xy[w][kk])[par] = _c;
                            p = __fadd_rn(_c, a);               // +0.0 bit-safe
                        }
                        if (k1 > kend) bd_h[w][par] = p;        // crossing-out (unique)
                    }
                }
            }
        }
        PBAR();   // bd_xy + handoff visible

        // ---- C: output assembly, dense stores ----
#pragma unroll
        for (int j = 0; j < JPP; ++j) {
            const int kk = lane + 64 * j;
            const int k = kb + kk;
            float2 xy = bd_xy[w][kk];
            float _x = xy.x, _y = xy.y;
            float o0 = __fmul_rn(_x, 1.0f / 512.0f);
            float o1 = __fmul_rn(_y, 1.0f / 384.0f);
            bool isl = rel[k] != 0.0f;
            float o4 = o0, o5 = o1;
            if (isl) {
                o4 = __fmul_rn(__fadd_rn(_x, e1r[j]), 1.0f / 512.0f);
                o5 = __fmul_rn(__fadd_rn(_y, e2r[j]), 1.0f / 384.0f);
            }
            float* op = orow + (size_t)k * 6;
            v2f a = {o0, o1};
            v2f b = {o2r[j], o3r[j]};
            v2f c = {o4, o5};
            *(v2f*)(op)     = a;
            *(v2f*)(op + 2) = b;
            *(v2f*)(op + 4) = c;
        }
        PBAR();   // C's bd_xy reads done before next A overwrites bd_pk/bd_xy
    }
}

extern "C" void kernel_launch(void* const* d_in, const int* in_sizes, int n_in,
                              void* d_out, int out_size, void* d_ws, size_t ws_size,
                              hipStream_t stream) {
    const float* mapvars = (const float*)d_in[0];
    const float* rel     = (const float*)d_in[1];
    const float* sp      = (const float*)d_in[2];
    const float* lm      = (const float*)d_in[3];
    const int*   nfse    = (const int*)d_in[4];
    float* out = (float*)d_out;

    const int B = in_sizes[0] / (4 * H);   // 32768
    hipLaunchKernelGGL(construct_map_seg, dim3(B / RPB), dim3(256), 0, stream,
                       mapvars, rel, sp, lm, nfse, out);
}

// Round 18
// 144.267 us; speedup vs baseline: 1.0887x; 1.0086x over previous
//
#include <hip/hip_runtime.h>
#include <math.h>

// KerasCustomMappingLayer: B=32768 rows x H=512 sequential steps, out (B,H,6) f32.
//
// R18 = R17 (proven 145.5us) with ONE subsystem change: BARRIER MINIMIZATION.
//   - s_w wall table double-buffered (s_w[2][HALF*2]); phase h writes the
//     table for phase h+1 (content depends only on read-only s_lk).
//   - With s_w handled by buffering, all A->B and B->C orderings touch only
//     per-wave arrays (bd_pk, bd_xy, bd_h) -> cross-lane-same-wave visibility
//     = wave-local "s_waitcnt lgkmcnt(0)" (asm, memory clobber, NO
//     sched_barrier per R15). Block barriers: 12/row -> 4/row (one PBAR at
//     phase top: lgkmcnt drain + raw s_barrier; vmcnt NOT drained so R17's
//     cross-phase mapvar prefetch stays in flight).
//   - Ordering proof: s_w[(h+1)&1] written in phase h, read by B(h+1): the
//     phase-(h+1) PBAR is between. Same buffer's previous readers B(h-1)
//     drained at their pre-C fence, ordered by phase-h PBAR. bd_pk/bd_xy/bd_h
//     are per-wave; writes drained at the adjacent wave fences.
//   - seg_list stored as short (values <= 512) to pay for the s_w double
//     buffer: LDS ~19.5KB -> 8 blocks/CU retained.
// Compute path untouched (identical ops, identical order) => bit-identical.
// R17: cross-phase register prefetch + non-draining barriers. R14: pair-split
// B + wall table ({-inf,+inf} at heads). R12: HALF=128. R11: packed bd_*,
// folded advance. R10: minimal-axis changes. Numerics: carry path
// bit-identical to numpy fp32 (contract off, IEEE div/sqrt); outputs *1/512
// pow2-exact, *1/384 <=1ulp output-only (absmax 0.0078125 stable R8-R17).
// Frozen: plain stores (R2/R4), dense global access (R1), no VGPR squeeze (R5).

#define H 512
#define RPB 4      // rows per block = waves per block
#define HALF 128   // k-steps staged per phase
#define NPH (H / HALF)
#define JPP (HALF / 64)   // j-iterations per phase
#define SLOTS 5    // 5*32 pairs = 160 >= max segments intersecting a phase

typedef float v2f __attribute__((ext_vector_type(2)));
typedef float v4f __attribute__((ext_vector_type(4)));

// block barrier WITHOUT vmcnt drain (LDS visibility across waves)
#define PBAR() do { \
    asm volatile("s_waitcnt lgkmcnt(0)" ::: "memory"); \
    __builtin_amdgcn_s_barrier(); \
} while (0)

// wave-local LDS fence (cross-lane visibility within the wave)
#define WF() do { \
    asm volatile("s_waitcnt lgkmcnt(0)" ::: "memory"); \
} while (0)

__global__ __launch_bounds__(256, 4)
void construct_map_seg(const float* __restrict__ mapvars,
                       const float* __restrict__ rel,
                       const float* __restrict__ start_pos,
                       const float* __restrict__ lmul,
                       const int* __restrict__ nfse_p,
                       float* __restrict__ out)
{
#pragma clang fp contract(off)
    __shared__ float s_lk[H];
    __shared__ short seg_list[H + 8];
    __shared__ int   nseg_s;
    __shared__ int   s_S[NPH];              // first segment intersecting each phase
    __shared__ float2 s_w[2][HALF * 2];     // double-buffered wall table; heads {-inf,+inf}
    __shared__ float2 bd_pk[RPB][HALF * 2]; // per-wave: {d_or_r, advance} per (kk,par)
    __shared__ float2 bd_xy[RPB][HALF];     // per-wave: {_x,_y} results
    __shared__ float  bd_h[RPB][2];         // per-wave: phase-crossing carry per chain

    const int tid = threadIdx.x;
    const int w = tid >> 6;
    const int lane = tid & 63;
    const int pair = lane >> 1;
    const int par = lane & 1;
    const int row = blockIdx.x * RPB + w;

    const float WL = (float)(0.05 * 512.0);
    const float WR = (float)(0.95 * 512.0);
    const float WT = (float)(0.05 * 384.0);
    const float WB = (float)(0.95 * 384.0);

    const float lm = lmul[0];
    for (int i = tid; i < H; i += 256)
        s_lk[i] = __fmul_rn(lm, rel[5 * H + i]);   // l = lmul * note_dist
    __syncthreads();

    // segment list: starts = {0} U {k : l[k] > 192}  (k-only, all rows share)
    if (tid < 64) {
        int base = 0;
        for (int c = 0; c < H / 64; ++c) {
            int k = c * 64 + tid;
            bool isr = (k == 0) || (s_lk[k] > 192.0f);
            unsigned long long m = __ballot(isr);
            int idx = base + __popcll(m & ((1ull << tid) - 1ull));
            if (isr) seg_list[idx] = (short)k;
            base += __popcll(m);
        }
        if (tid == 0) { seg_list[base] = (short)H; nseg_s = base; }
        // per-phase first-intersecting segment: S_h = (first idx > kb) - 1
        if (tid < NPH) {
            int kb = tid * HALF;
            int lo = 0, hi = base + 1;
            while (lo < hi) { int m = (lo + hi) >> 1; if ((int)seg_list[m] <= kb) lo = m + 1; else hi = m; }
            s_S[tid] = lo - 1;                     // seg_list[0]=0 => S>=0
        }
    }
    // prologue: wall table for phase 0 into buffer 0
    {
        const int i = tid;
        const int kkw = i >> 1, prw = i & 1;
        float lk = s_lk[kkw];                      // phase 0: kb = 0
        bool head = lk > 192.0f;
        float hl = __fmul_rn(lk, 0.5f);
        float blo = prw ? WT : WL;
        float bhi = prw ? WB : WR;
        v2f w2 = {head ? -INFINITY : __fadd_rn(blo, hl),
                  head ?  INFINITY : __fadd_rn(bhi, -hl)};
        *(v2f*)&s_w[0][i] = w2;
    }
    __syncthreads();

    const int nseg = nseg_s;
    const bool nfse = (nfse_p[0] != 0);
    const float sx = start_pos[0], sy = start_pos[1];

    // fresh-segment init for k==0: start_pos unless k==0 is itself a rerand head
    const bool head0 = s_lk[0] > 192.0f;
    const float pinit0 = head0 ? 0.0f : (par ? sy : sx);

    const float* rowp = mapvars + (size_t)row * (4 * H);
    float* orow = out + (size_t)row * (H * 6);

    // ---- cross-phase register prefetch of mapvars (8 VGPRs) ----
    float pf[JPP][4];
#pragma unroll
    for (int j = 0; j < JPP; ++j) {
        const int k = lane + 64 * j;                  // phase 0
        pf[j][0] = rowp[k];
        pf[j][1] = rowp[H + k];
        pf[j][2] = rowp[2 * H + k];
        pf[j][3] = rowp[3 * H + k];
    }

    for (int h = 0; h < NPH; ++h) {
        const int kb = h * HALF;
        const int kend = kb + HALF;
        const int kbn = ((h + 1) & (NPH - 1)) * HALF; // next phase base (wraps)
        float o2r[JPP], o3r[JPP], e1r[JPP], e2r[JPP];

        if (h) PBAR();   // the ONLY block barrier per phase (no vmcnt drain)

        // ---- wall table for NEXT phase into buffer (h+1)&1 ----
        {
            const int i = tid;
            const int kkw = i >> 1, prw = i & 1;
            float lk = s_lk[kbn + kkw];
            bool head = lk > 192.0f;
            float hl = __fmul_rn(lk, 0.5f);
            float blo = prw ? WT : WL;
            float bhi = prw ? WB : WR;
            v2f w2 = {head ? -INFINITY : __fadd_rn(blo, hl),
                      head ?  INFINITY : __fadd_rn(bhi, -hl)};
            *(v2f*)&s_w[(h + 1) & 1][i] = w2;
        }

        // ---- A: consume prefetched regs, compute, issue next-phase loads ----
#pragma unroll
        for (int j = 0; j < JPP; ++j) {
            const int kk = lane + 64 * j;
            const int k = kb + kk;
            float m0 = pf[j][0];
            float m1 = pf[j][1];
            float m2 = pf[j][2];
            float m3 = pf[j][3];
            {
                const int kn = kbn + kk;
                pf[j][0] = rowp[kn];
                pf[j][1] = rowp[H + kn];
                pf[j][2] = rowp[2 * H + kn];
                pf[j][3] = rowp[3 * H + kn];
            }
            float sln  = rel[H + k];
            float scos = rel[3 * H + k];
            float ssin = rel[4 * H + k];
            float lk  = s_lk[k];
            float isf = rel[k];                       // is_slider (L2-broadcast)

            float len1 = __fsqrt_rn(__fadd_rn(__fmul_rn(m0, m0), __fmul_rn(m2, m2)));
            float ck = __fdiv_rn(m0, len1);
            float sk = __fdiv_rn(m2, len1);
            float len2 = __fsqrt_rn(__fadd_rn(__fmul_rn(m1, m1), __fmul_rn(m3, m3)));
            float ck2 = __fdiv_rn(m1, len2);
            float sk2 = __fdiv_rn(m3, len2);

            float dx = __fmul_rn(lk, ck);
            float dy = __fmul_rn(lk, sk);
            float rx = __fadd_rn(256.0f, __fmul_rn(256.0f, m0));
            float ry = __fadd_rn(192.0f, __fmul_rn(192.0f, m2));
            float e1 = __fmul_rn(ck2, sln);
            float e2 = __fmul_rn(sk2, sln);
            bool rr  = lk > 192.0f;                   // head position
            bool isl = isf != 0.0f;
            float oa = __fadd_rn(__fmul_rn(ck2, scos), -__fmul_rn(sk2, ssin));
            float ob = __fadd_rn(__fmul_rn(ck2, ssin),  __fmul_rn(sk2, scos));
            o2r[j] = isl ? oa : (rr ? ck2 : ck);
            o3r[j] = isl ? ob : (rr ? sk2 : sk);
            e1r[j] = e1; e2r[j] = e2;

            bool adv = isl && nfse;
            v4f pk4 = {rr ? rx : dx, adv ? e1 : 0.0f,
                       rr ? ry : dy, adv ? e2 : 0.0f};
            *(v4f*)&bd_pk[w][2 * kk] = pk4;           // one b128 store
        }
        WF();   // bd_pk visible wave-wide (per-wave array; cross-lane in-wave)

        // ---- B: serial carry chain, pair-split (R14 form) ----
        {
            const int S = s_S[h];
            const float2* swb = &s_w[h & 1][0];
#pragma unroll
            for (int slot = 0; slot < SLOTS; ++slot) {
                const int sid = S + pair + 32 * slot;
                if (sid < nseg) {
                    const int k0 = seg_list[sid];
                    const int k1 = seg_list[sid + 1];
                    const int lo = (k0 > kb) ? k0 : kb;
                    const int hi = (k1 < kend) ? k1 : kend;
                    if (lo < hi) {
                        float p;
                        if (k0 < kb)      p = bd_h[w][par];     // crossing-in
                        else if (k0 == 0) p = pinit0;
                        else              p = 0.0f;             // fresh head segment
                        for (int k = lo; k < hi; ++k) {
                            const int kk = k - kb;
                            float2 w2 = swb[2 * kk + par];
                            float2 pk = bd_pk[w][2 * kk + par];
                            float d = pk.x, a = pk.y;
                            float ad = fabsf(d);
                            float cd = (p < w2.x) ? ad
                                     : ((p > w2.y) ? -ad
                                     : (((p > w2.x) && (p < w2.y)) ? d : 0.0f));
                            float _c = __fadd_rn(p, cd);        // head: 0 + r = r
                            ((float*)&bd_xy[w][kk])[par] = _c;
                            p = __fadd_rn(_c, a);               // +0.0 bit-safe
                        }
                        if (k1 > kend) bd_h[w][par] = p;        // crossing-out (unique)
                    }
                }
            }
        }
        WF();   // bd_xy + bd_h visible wave-wide

        // ---- C: output assembly, dense stores ----
#pragma unroll
        for (int j = 0; j < JPP; ++j) {
            const int kk = lane + 64 * j;
            const int k = kb + kk;
            float2 xy = bd_xy[w][kk];
            float _x = xy.x, _y = xy.y;
            float o0 = __fmul_rn(_x, 1.0f / 512.0f);
            float o1 = __fmul_rn(_y, 1.0f / 384.0f);
            bool isl = rel[k] != 0.0f;
            float o4 = o0, o5 = o1;
            if (isl) {
                o4 = __fmul_rn(__fadd_rn(_x, e1r[j]), 1.0f / 512.0f);
                o5 = __fmul_rn(__fadd_rn(_y, e2r[j]), 1.0f / 384.0f);
            }
            float* op = orow + (size_t)k * 6;
            v2f a = {o0, o1};
            v2f b = {o2r[j], o3r[j]};
            v2f c = {o4, o5};
            *(v2f*)(op)     = a;
            *(v2f*)(op + 2) = b;
            *(v2f*)(op + 4) = c;
        }
        // no fence here: C's bd_xy reads are drained by the next phase's
        // A->B WF (same wave); s_w buffer reuse is ordered by the phase PBAR.
    }
}

extern "C" void kernel_launch(void* const* d_in, const int* in_sizes, int n_in,
                              void* d_out, int out_size, void* d_ws, size_t ws_size,
                              hipStream_t stream) {
    const float* mapvars = (const float*)d_in[0];
    const float* rel     = (const float*)d_in[1];
    const float* sp      = (const float*)d_in[2];
    const float* lm      = (const float*)d_in[3];
    const int*   nfse    = (const int*)d_in[4];
    float* out = (float*)d_out;

    const int B = in_sizes[0] / (4 * H);   // 32768
    hipLaunchKernelGGL(construct_map_seg, dim3(B / RPB), dim3(256), 0, stream,
                       mapvars, rel, sp, lm, nfse, out);
}

// Round 19
// 142.599 us; speedup vs baseline: 1.1015x; 1.0117x over previous
//
#include <hip/hip_runtime.h>
#include <math.h>

// KerasCustomMappingLayer: B=32768 rows x H=512 sequential steps, out (B,H,6) f32.
//
// R19 = R18 (proven 144.3us) with ONE change: kill the WRAPPED DEAD PREFETCH.
//   R17/R18's cross-phase mapvar prefetch wrapped at h=NPH-1 to phase 0,
//   issuing 8 never-consumed global loads per j-group: 2KB/row x 32768 rows
//   = ~64MB dead fetch (~12% of the read stream, mostly L2-evicted by then).
//   Now guarded by (h+1 < NPH) -- wave-uniform, unrollable; pf keeps stale
//   values through the last phase (never read). No consumed value changes.
// R18: 1 block barrier/phase (double-buffered s_w, wave-local WF fences,
//      short seg_list). R17: cross-phase register prefetch + non-draining
//      PBAR (no vmcnt drain). R14: pair-split B + wall table ({-inf,+inf}
//      heads). R12: HALF=128, 8 blocks/CU. R11: packed bd_*, folded advance.
// Numerics: carry path bit-identical to numpy fp32 (contract off, IEEE
// div/sqrt); outputs *1/512 pow2-exact, *1/384 <=1ulp output-only
// (absmax 0.0078125 stable R8-R18).
// Frozen: plain stores (R2/R4), dense global access (R1), no VGPR squeeze
// (R5), no sched_barrier (R15), single-axis change (R10).

#define H 512
#define RPB 4      // rows per block = waves per block
#define HALF 128   // k-steps staged per phase
#define NPH (H / HALF)
#define JPP (HALF / 64)   // j-iterations per phase
#define SLOTS 5    // 5*32 pairs = 160 >= max segments intersecting a phase

typedef float v2f __attribute__((ext_vector_type(2)));
typedef float v4f __attribute__((ext_vector_type(4)));

// block barrier WITHOUT vmcnt drain (LDS visibility across waves)
#define PBAR() do { \
    asm volatile("s_waitcnt lgkmcnt(0)" ::: "memory"); \
    __builtin_amdgcn_s_barrier(); \
} while (0)

// wave-local LDS fence (cross-lane visibility within the wave)
#define WF() do { \
    asm volatile("s_waitcnt lgkmcnt(0)" ::: "memory"); \
} while (0)

__global__ __launch_bounds__(256, 4)
void construct_map_seg(const float* __restrict__ mapvars,
                       const float* __restrict__ rel,
                       const float* __restrict__ start_pos,
                       const float* __restrict__ lmul,
                       const int* __restrict__ nfse_p,
                       float* __restrict__ out)
{
#pragma clang fp contract(off)
    __shared__ float s_lk[H];
    __shared__ short seg_list[H + 8];
    __shared__ int   nseg_s;
    __shared__ int   s_S[NPH];              // first segment intersecting each phase
    __shared__ float2 s_w[2][HALF * 2];     // double-buffered wall table; heads {-inf,+inf}
    __shared__ float2 bd_pk[RPB][HALF * 2]; // per-wave: {d_or_r, advance} per (kk,par)
    __shared__ float2 bd_xy[RPB][HALF];     // per-wave: {_x,_y} results
    __shared__ float  bd_h[RPB][2];         // per-wave: phase-crossing carry per chain

    const int tid = threadIdx.x;
    const int w = tid >> 6;
    const int lane = tid & 63;
    const int pair = lane >> 1;
    const int par = lane & 1;
    const int row = blockIdx.x * RPB + w;

    const float WL = (float)(0.05 * 512.0);
    const float WR = (float)(0.95 * 512.0);
    const float WT = (float)(0.05 * 384.0);
    const float WB = (float)(0.95 * 384.0);

    const float lm = lmul[0];
    for (int i = tid; i < H; i += 256)
        s_lk[i] = __fmul_rn(lm, rel[5 * H + i]);   // l = lmul * note_dist
    __syncthreads();

    // segment list: starts = {0} U {k : l[k] > 192}  (k-only, all rows share)
    if (tid < 64) {
        int base = 0;
        for (int c = 0; c < H / 64; ++c) {
            int k = c * 64 + tid;
            bool isr = (k == 0) || (s_lk[k] > 192.0f);
            unsigned long long m = __ballot(isr);
            int idx = base + __popcll(m & ((1ull << tid) - 1ull));
            if (isr) seg_list[idx] = (short)k;
            base += __popcll(m);
        }
        if (tid == 0) { seg_list[base] = (short)H; nseg_s = base; }
        // per-phase first-intersecting segment: S_h = (first idx > kb) - 1
        if (tid < NPH) {
            int kb = tid * HALF;
            int lo = 0, hi = base + 1;
            while (lo < hi) { int m = (lo + hi) >> 1; if ((int)seg_list[m] <= kb) lo = m + 1; else hi = m; }
            s_S[tid] = lo - 1;                     // seg_list[0]=0 => S>=0
        }
    }
    // prologue: wall table for phase 0 into buffer 0
    {
        const int i = tid;
        const int kkw = i >> 1, prw = i & 1;
        float lk = s_lk[kkw];                      // phase 0: kb = 0
        bool head = lk > 192.0f;
        float hl = __fmul_rn(lk, 0.5f);
        float blo = prw ? WT : WL;
        float bhi = prw ? WB : WR;
        v2f w2 = {head ? -INFINITY : __fadd_rn(blo, hl),
                  head ?  INFINITY : __fadd_rn(bhi, -hl)};
        *(v2f*)&s_w[0][i] = w2;
    }
    __syncthreads();

    const int nseg = nseg_s;
    const bool nfse = (nfse_p[0] != 0);
    const float sx = start_pos[0], sy = start_pos[1];

    // fresh-segment init for k==0: start_pos unless k==0 is itself a rerand head
    const bool head0 = s_lk[0] > 192.0f;
    const float pinit0 = head0 ? 0.0f : (par ? sy : sx);

    const float* rowp = mapvars + (size_t)row * (4 * H);
    float* orow = out + (size_t)row * (H * 6);

    // ---- cross-phase register prefetch of mapvars (8 VGPRs) ----
    float pf[JPP][4];
#pragma unroll
    for (int j = 0; j < JPP; ++j) {
        const int k = lane + 64 * j;                  // phase 0
        pf[j][0] = rowp[k];
        pf[j][1] = rowp[H + k];
        pf[j][2] = rowp[2 * H + k];
        pf[j][3] = rowp[3 * H + k];
    }

    for (int h = 0; h < NPH; ++h) {
        const int kb = h * HALF;
        const int kend = kb + HALF;
        const int kbn = ((h + 1) & (NPH - 1)) * HALF; // next phase base
        float o2r[JPP], o3r[JPP], e1r[JPP], e2r[JPP];

        if (h) PBAR();   // the ONLY block barrier per phase (no vmcnt drain)

        // ---- wall table for NEXT phase into buffer (h+1)&1 ----
        {
            const int i = tid;
            const int kkw = i >> 1, prw = i & 1;
            float lk = s_lk[kbn + kkw];
            bool head = lk > 192.0f;
            float hl = __fmul_rn(lk, 0.5f);
            float blo = prw ? WT : WL;
            float bhi = prw ? WB : WR;
            v2f w2 = {head ? -INFINITY : __fadd_rn(blo, hl),
                      head ?  INFINITY : __fadd_rn(bhi, -hl)};
            *(v2f*)&s_w[(h + 1) & 1][i] = w2;
        }

        // ---- A: consume prefetched regs, compute, issue next-phase loads ----
#pragma unroll
        for (int j = 0; j < JPP; ++j) {
            const int kk = lane + 64 * j;
            const int k = kb + kk;
            float m0 = pf[j][0];
            float m1 = pf[j][1];
            float m2 = pf[j][2];
            float m3 = pf[j][3];
            if (h + 1 < NPH) {                        // no dead wrap-prefetch (R19)
                const int kn = kbn + kk;
                pf[j][0] = rowp[kn];
                pf[j][1] = rowp[H + kn];
                pf[j][2] = rowp[2 * H + kn];
                pf[j][3] = rowp[3 * H + kn];
            }
            float sln  = rel[H + k];
            float scos = rel[3 * H + k];
            float ssin = rel[4 * H + k];
            float lk  = s_lk[k];
            float isf = rel[k];                       // is_slider (L2-broadcast)

            float len1 = __fsqrt_rn(__fadd_rn(__fmul_rn(m0, m0), __fmul_rn(m2, m2)));
            float ck = __fdiv_rn(m0, len1);
            float sk = __fdiv_rn(m2, len1);
            float len2 = __fsqrt_rn(__fadd_rn(__fmul_rn(m1, m1), __fmul_rn(m3, m3)));
            float ck2 = __fdiv_rn(m1, len2);
            float sk2 = __fdiv_rn(m3, len2);

            float dx = __fmul_rn(lk, ck);
            float dy = __fmul_rn(lk, sk);
            float rx = __fadd_rn(256.0f, __fmul_rn(256.0f, m0));
            float ry = __fadd_rn(192.0f, __fmul_rn(192.0f, m2));
            float e1 = __fmul_rn(ck2, sln);
            float e2 = __fmul_rn(sk2, sln);
            bool rr  = lk > 192.0f;                   // head position
            bool isl = isf != 0.0f;
            float oa = __fadd_rn(__fmul_rn(ck2, scos), -__fmul_rn(sk2, ssin));
            float ob = __fadd_rn(__fmul_rn(ck2, ssin),  __fmul_rn(sk2, scos));
            o2r[j] = isl ? oa : (rr ? ck2 : ck);
            o3r[j] = isl ? ob : (rr ? sk2 : sk);
            e1r[j] = e1; e2r[j] = e2;

            bool adv = isl && nfse;
            v4f pk4 = {rr ? rx : dx, adv ? e1 : 0.0f,
                       rr ? ry : dy, adv ? e2 : 0.0f};
            *(v4f*)&bd_pk[w][2 * kk] = pk4;           // one b128 store
        }
        WF();   // bd_pk visible wave-wide (per-wave array; cross-lane in-wave)

        // ---- B: serial carry chain, pair-split (R14 form) ----
        {
            const int S = s_S[h];
            const float2* swb = &s_w[h & 1][0];
#pragma unroll
            for (int slot = 0; slot < SLOTS; ++slot) {
                const int sid = S + pair + 32 * slot;
                if (sid < nseg) {
                    const int k0 = seg_list[sid];
                    const int k1 = seg_list[sid + 1];
                    const int lo = (k0 > kb) ? k0 : kb;
                    const int hi = (k1 < kend) ? k1 : kend;
                    if (lo < hi) {
                        float p;
                        if (k0 < kb)      p = bd_h[w][par];     // crossing-in
                        else if (k0 == 0) p = pinit0;
                        else              p = 0.0f;             // fresh head segment
                        for (int k = lo; k < hi; ++k) {
                            const int kk = k - kb;
                            float2 w2 = swb[2 * kk + par];
                            float2 pk = bd_pk[w][2 * kk + par];
                            float d = pk.x, a = pk.y;
                            float ad = fabsf(d);
                            float cd = (p < w2.x) ? ad
                                     : ((p > w2.y) ? -ad
                                     : (((p > w2.x) && (p < w2.y)) ? d : 0.0f));
                            float _c = __fadd_rn(p, cd);        // head: 0 + r = r
                            ((float*)&bd_xy[w][kk])[par] = _c;
                            p = __fadd_rn(_c, a);               // +0.0 bit-safe
                        }
                        if (k1 > kend) bd_h[w][par] = p;        // crossing-out (unique)
                    }
                }
            }
        }
        WF();   // bd_xy + bd_h visible wave-wide

        // ---- C: output assembly, dense stores ----
#pragma unroll
        for (int j = 0; j < JPP; ++j) {
            const int kk = lane + 64 * j;
            const int k = kb + kk;
            float2 xy = bd_xy[w][kk];
            float _x = xy.x, _y = xy.y;
            float o0 = __fmul_rn(_x, 1.0f / 512.0f);
            float o1 = __fmul_rn(_y, 1.0f / 384.0f);
            bool isl = rel[k] != 0.0f;
            float o4 = o0, o5 = o1;
            if (isl) {
                o4 = __fmul_rn(__fadd_rn(_x, e1r[j]), 1.0f / 512.0f);
                o5 = __fmul_rn(__fadd_rn(_y, e2r[j]), 1.0f / 384.0f);
            }
            float* op = orow + (size_t)k * 6;
            v2f a = {o0, o1};
            v2f b = {o2r[j], o3r[j]};
            v2f c = {o4, o5};
            *(v2f*)(op)     = a;
            *(v2f*)(op + 2) = b;
            *(v2f*)(op + 4) = c;
        }
        // no fence here: C's bd_xy reads are drained by the next phase's
        // A->B WF (same wave); s_w buffer reuse is ordered by the phase PBAR.
    }
}

extern "C" void kernel_launch(void* const* d_in, const int* in_sizes, int n_in,
                              void* d_out, int out_size, void* d_ws, size_t ws_size,
                              hipStream_t stream) {
    const float* mapvars = (const float*)d_in[0];
    const float* rel     = (const float*)d_in[1];
    const float* sp      = (const float*)d_in[2];
    const float* lm      = (const float*)d_in[3];
    const int*   nfse    = (const int*)d_in[4];
    float* out = (float*)d_out;

    const int B = in_sizes[0] / (4 * H);   // 32768
    hipLaunchKernelGGL(construct_map_seg, dim3(B / RPB), dim3(256), 0, stream,
                       mapvars, rel, sp, lm, nfse, out);
}